// Round 2
// baseline (451.633 us; speedup 1.0000x reference)
//
#include <hip/hip_runtime.h>
#include <cstdint>

// Instant-NGP hash-grid embedder — R7: FUSED TAIL TRANSPOSE (single hot kernel).
//
// History / journal:
//  R2: level->XCD affinity (blockIdx%8 pins level pairs (i,15-i)); FETCH
//      1.56GB -> 149MB. Phase A = 226us ~= 97% of per-XCD L2 random-gather
//      request roofline. R5: more per-thread work does NOT help (req-bound).
//  R4: no __builtin_nontemporal_* (regressed both phases).
//  R5: phase-B store coalescing (64x16B strided -> 1KB runs): NEUTRAL.
//  R6: phase-B chunk-major contiguous reads (kill 4MB-stride theory): NEUTRAL.
//      => phase B (~110us) is insensitive to BOTH its read and store
//      patterns; models say it should cost 15-25us. Conclusion: the cost is
//      the *serialized second dispatch*, not its memory pattern. R7 fuses
//      the transpose into phase A as a per-chunk tail and overlaps it.
//
// R7 mechanism:
//  - ws stores are AGENT-scope (sc1) 8B atomic stores: coherent at L3,
//    per-line, so NO buffer_wbl2/buffer_inv cache-wide ops (those would
//    evict the hot table slice from L2 and wreck the gather roofline).
//  - __syncthreads() drains vmcnt(0) per wave -> all block stores acked at
//    the coherence point BEFORE thread 0's atomicAdd(counter[chunk]).
//  - The 16th arriver transposes chunk c (reads ws via agent-scope loads —
//    immune to stale lines cached by a PREVIOUS iteration's transpose on
//    this XCD). Transpose = 2 half-passes of 128 pts, LDS 32x129 floats
//    (16.5KB, <=2-way banks = free), 1KB-contiguous out stores.
//  - No spinning: only completed blocks do extra work -> no deadlock, no
//    cooperative launch, dispatch-order independent (G16-safe).
//
// Discrete steps (bottom_left trunc) replicated in float64 to match the
// NumPy reference under NEP-50 promotion. Resolutions hardcoded to the
// exact-math floor(16 * 2^(l/3)) values.

constexpr int NLEV = 16;
constexpr uint32_t HM_MASK = (1u << 19) - 1;

__device__ __constant__ double c_res[NLEV] = {
    16.0, 20.0, 25.0, 32.0, 40.0, 50.0, 64.0, 80.0,
    101.0, 128.0, 161.0, 203.0, 256.0, 322.0, 406.0, 512.0
};

__device__ __forceinline__ void ngp_eval_point(
    int b, int lev,
    const float* __restrict__ x,
    const float2* __restrict__ tab2,
    float bm0, float bm1, float bm2,
    float d0, float d1, float d2,
    float& f0, float& f1)
{
    const float fx0 = x[3 * b + 0];
    const float fx1 = x[3 * b + 1];
    const float fx2 = x[3 * b + 2];

    const double res = c_res[lev];
    const double g0 = (double)d0 / res;
    const double g1 = (double)d1 / res;
    const double g2 = (double)d2 / res;
    const double q0 = (double)(fx0 - bm0) / g0;
    const double q1 = (double)(fx1 - bm1) / g1;
    const double q2 = (double)(fx2 - bm2) / g2;
    const int i0 = (int)q0;
    const int i1 = (int)q1;
    const int i2 = (int)q2;
    const float w0 = (float)(q0 - (double)i0);
    const float w1 = (float)(q1 - (double)i1);
    const float w2 = (float)(q2 - (double)i2);

    const uint32_t P1 = 2654435761u, P2 = 805459861u;
    const uint32_t h0a = (uint32_t)i0;
    const uint32_t h0b = h0a + 1u;
    const uint32_t h1a = (uint32_t)i1 * P1;
    const uint32_t h1b = h1a + P1;
    const uint32_t h2a = (uint32_t)i2 * P2;
    const uint32_t h2b = h2a + P2;
    const uint32_t base = (uint32_t)lev << 19;

    const float2 v000 = tab2[base + ((h0a ^ h1a ^ h2a) & HM_MASK)];
    const float2 v001 = tab2[base + ((h0a ^ h1a ^ h2b) & HM_MASK)];
    const float2 v010 = tab2[base + ((h0a ^ h1b ^ h2a) & HM_MASK)];
    const float2 v011 = tab2[base + ((h0a ^ h1b ^ h2b) & HM_MASK)];
    const float2 v100 = tab2[base + ((h0b ^ h1a ^ h2a) & HM_MASK)];
    const float2 v101 = tab2[base + ((h0b ^ h1a ^ h2b) & HM_MASK)];
    const float2 v110 = tab2[base + ((h0b ^ h1b ^ h2a) & HM_MASK)];
    const float2 v111 = tab2[base + ((h0b ^ h1b ^ h2b) & HM_MASK)];

    const float u0 = 1.0f - w0, u1 = 1.0f - w1, u2 = 1.0f - w2;
    const float waa = u1 * u2;
    const float wab = u1 * w2;
    const float wba = w1 * u2;
    const float wbb = w1 * w2;

    f0 = u0 * (waa * v000.x + wab * v001.x + wba * v010.x + wbb * v011.x)
       + w0 * (waa * v100.x + wab * v101.x + wba * v110.x + wbb * v111.x);
    f1 = u0 * (waa * v000.y + wab * v001.y + wba * v010.y + wbb * v011.y)
       + w0 * (waa * v100.y + wab * v101.y + wba * v110.y + wbb * v111.y);
}

// ---------------- counter zeroing (graph-capturable tiny kernel) ------------
__global__ __launch_bounds__(256)
void ngp_zero_counters(int* __restrict__ counters, int n)
{
    const int i = blockIdx.x * 256 + threadIdx.x;
    if (i < n) counters[i] = 0;
}

// ---------------- R7 fused kernel: gather+interp, last-arriver transpose ----
// Grid = 8 residues x 2 levels x chunks. Requires B % 256 == 0.
// LDS: rows r = 2l+f (32 rows) x 128 pts, stride 129 floats = 16512 B
// (<=2-way bank aliasing on both stages = free per m136).
__global__ __launch_bounds__(256)
void ngp_fused_tail_kernel(const float* __restrict__ x,
                           const float* __restrict__ table,
                           const float* __restrict__ box_min,
                           const float* __restrict__ box_max,
                           float2* __restrict__ ws,
                           int* __restrict__ counters,
                           float* __restrict__ out,
                           int B, int chunks)
{
    __shared__ float lds[32 * 129];
    __shared__ int s_last;

    // XCD-affinity: residue = blockIdx%8 -> XCD (HW round-robin dispatch).
    // Residue i: level i (first half of grid, coarse) then 15-i (fine).
    const int xcd = blockIdx.x & 7;
    const int s   = blockIdx.x >> 3;
    const int lev   = (s < chunks) ? xcd : (15 - xcd);
    const int chunk = (s < chunks) ? s : (s - chunks);
    const int t = threadIdx.x;
    const int b = chunk * 256 + t;

    const float bm0 = box_min[0], bm1 = box_min[1], bm2 = box_min[2];
    const float d0 = box_max[0] - bm0;
    const float d1 = box_max[1] - bm1;
    const float d2 = box_max[2] - bm2;

    float f0, f1;
    ngp_eval_point(b, lev, x, (const float2*)table,
                   bm0, bm1, bm2, d0, d1, d2, f0, f1);

    // chunk-major ws [chunk][level][point], agent-scope (sc1) 8B store:
    // write-through to the coherence point, per-line — table lines in L2
    // stay untouched (no cache-wide flush).
    {
        float2 v = make_float2(f0, f1);
        unsigned long long raw;
        __builtin_memcpy(&raw, &v, 8);
        __hip_atomic_store(
            (unsigned long long*)&ws[(size_t)chunk * (NLEV * 256) + lev * 256 + t],
            raw, __ATOMIC_RELAXED, __HIP_MEMORY_SCOPE_AGENT);
    }

    // All waves drain vmcnt(0) at the barrier -> every store of this block
    // is acked at agent scope before the counter bump below.
    __syncthreads();

    if (t == 0) {
        const int old = atomicAdd(&counters[chunk], 1);  // device-scope RMW
        s_last = (old == NLEV - 1);
    }
    __syncthreads();
    if (!s_last) return;

    // ---- last arriver: transpose chunk -> out[b][f*16+l] -------------------
    // compiler barrier: keep the ws loads below the completion check
    asm volatile("" ::: "memory");

    const float2* __restrict__ wsc = ws + (size_t)chunk * (NLEV * 256);
    const int p_lo = t >> 3;
    const int f    = (t >> 2) & 1;
    const int l0   = (t & 3) * 4;

#pragma unroll
    for (int h = 0; h < 2; ++h) {
        // Stage 1: 8 iters cover 16 levels x 128 pts; per wave one 512B
        // contiguous run. Agent-scope loads: fetch from the coherence point
        // (immune to stale L2 lines cached by a previous iteration).
#pragma unroll
        for (int i = 0; i < 8; ++i) {
            const int l = 2 * i + (t >> 7);
            const int p = t & 127;
            unsigned long long raw = __hip_atomic_load(
                (const unsigned long long*)&wsc[l * 256 + h * 128 + p],
                __ATOMIC_RELAXED, __HIP_MEMORY_SCOPE_AGENT);
            float2 v;
            __builtin_memcpy(&v, &raw, 8);
            lds[(2 * l)     * 129 + p] = v.x;
            lds[(2 * l + 1) * 129 + p] = v.y;
        }
        __syncthreads();

        // Stage 2: each store instr writes 1KB contiguous.
        // Lane t, iter j: point p = j*32 + (t>>3), cols [(t&7)*4, +4).
        float* outh = out + ((size_t)chunk * 256 + h * 128) * 32;
#pragma unroll
        for (int j = 0; j < 4; ++j) {
            const int p = j * 32 + p_lo;
            float4 o;
            o.x = lds[(2 * (l0 + 0) + f) * 129 + p];
            o.y = lds[(2 * (l0 + 1) + f) * 129 + p];
            o.z = lds[(2 * (l0 + 2) + f) * 129 + p];
            o.w = lds[(2 * (l0 + 3) + f) * 129 + p];
            *(float4*)(outh + j * 1024 + t * 4) = o;
        }
        __syncthreads();  // protect LDS before next half-pass overwrites
    }
}

// ---------------- Fallback path 1: proven R6 two-kernel pipeline ------------
__global__ __launch_bounds__(256)
void ngp_levels_kernel(const float* __restrict__ x,
                       const float* __restrict__ table,
                       const float* __restrict__ box_min,
                       const float* __restrict__ box_max,
                       float2* __restrict__ ws,
                       int B, int chunks)
{
    const int xcd = blockIdx.x & 7;
    const int s   = blockIdx.x >> 3;
    const int lev   = (s < chunks) ? xcd : (15 - xcd);
    const int chunk = (s < chunks) ? s : (s - chunks);
    const int b = chunk * 256 + threadIdx.x;
    if (b >= B) return;

    const float bm0 = box_min[0], bm1 = box_min[1], bm2 = box_min[2];
    const float d0 = box_max[0] - bm0;
    const float d1 = box_max[1] - bm1;
    const float d2 = box_max[2] - bm2;

    float f0, f1;
    ngp_eval_point(b, lev, x, (const float2*)table,
                   bm0, bm1, bm2, d0, d1, d2, f0, f1);

    ws[(size_t)chunk * (NLEV * 256) + lev * 256 + threadIdx.x]
        = make_float2(f0, f1);
}

constexpr int LDS_STRIDE = 257;

__global__ __launch_bounds__(256)
void ngp_transpose_kernel(const float2* __restrict__ ws,
                          float* __restrict__ out,
                          int B)
{
    __shared__ float lds[32 * LDS_STRIDE];

    const int t  = threadIdx.x;
    const int c  = blockIdx.x;
    const int P0 = c * 256;

    const float2* __restrict__ wsc = ws + (size_t)c * (NLEV * 256);
#pragma unroll
    for (int l = 0; l < NLEV; ++l) {
        const float2 v = wsc[l * 256 + t];
        lds[(2 * l)     * LDS_STRIDE + t] = v.x;
        lds[(2 * l + 1) * LDS_STRIDE + t] = v.y;
    }
    __syncthreads();

    const int p_lo = t >> 3;
    const int f    = (t >> 2) & 1;
    const int l0   = (t & 3) * 4;
#pragma unroll
    for (int j = 0; j < 8; ++j) {
        const int p = j * 32 + p_lo;
        float4 v;
        v.x = lds[(2 * (l0 + 0) + f) * LDS_STRIDE + p];
        v.y = lds[(2 * (l0 + 1) + f) * LDS_STRIDE + p];
        v.z = lds[(2 * (l0 + 2) + f) * LDS_STRIDE + p];
        v.w = lds[(2 * (l0 + 3) + f) * LDS_STRIDE + p];
        *(float4*)(out + (size_t)P0 * 32 + j * 1024 + t * 4) = v;
    }
}

// ---------------- Fallback path 2: fused per-(point,level) kernel -----------
__global__ __launch_bounds__(256)
void ngp_embed_fused_kernel(const float* __restrict__ x,
                            const float* __restrict__ table,
                            const float* __restrict__ box_min,
                            const float* __restrict__ box_max,
                            float* __restrict__ out,
                            int B)
{
    const int gid = blockIdx.x * 256 + threadIdx.x;
    const int b = gid >> 4;
    const int l = gid & 15;
    if (b >= B) return;

    const float bm0 = box_min[0], bm1 = box_min[1], bm2 = box_min[2];
    const float d0 = box_max[0] - bm0;
    const float d1 = box_max[1] - bm1;
    const float d2 = box_max[2] - bm2;

    float f0, f1;
    ngp_eval_point(b, l, x, (const float2*)table,
                   bm0, bm1, bm2, d0, d1, d2, f0, f1);

    out[b * 32 + l]      = f0;
    out[b * 32 + 16 + l] = f1;
}

extern "C" void kernel_launch(void* const* d_in, const int* in_sizes, int n_in,
                              void* d_out, int out_size, void* d_ws, size_t ws_size,
                              hipStream_t stream) {
    const float* x       = (const float*)d_in[0];
    const float* table   = (const float*)d_in[1];
    const float* box_min = (const float*)d_in[2];
    const float* box_max = (const float*)d_in[3];
    float* out = (float*)d_out;

    const int B = in_sizes[0] / 3;
    const int chunks = B / 256;
    const size_t ws_data  = (size_t)B * NLEV * sizeof(float2);
    const size_t ws_fused = ws_data + (size_t)chunks * sizeof(int);

    if ((B % 256) == 0 && ws_size >= ws_fused) {
        // R7 fused path: zero per-chunk counters, then single fused kernel.
        int* counters = (int*)((char*)d_ws + ws_data);
        const int zblocks = (chunks + 255) / 256;
        hipLaunchKernelGGL(ngp_zero_counters, dim3(zblocks), dim3(256), 0, stream,
                           counters, chunks);
        const int gridA = 8 * 2 * chunks;
        hipLaunchKernelGGL(ngp_fused_tail_kernel, dim3(gridA), dim3(256), 0, stream,
                           x, table, box_min, box_max,
                           (float2*)d_ws, counters, out, B, chunks);
    } else if ((B % 256) == 0 && ws_size >= ws_data) {
        const int gridA = 8 * 2 * chunks;
        hipLaunchKernelGGL(ngp_levels_kernel, dim3(gridA), dim3(256), 0, stream,
                           x, table, box_min, box_max, (float2*)d_ws, B, chunks);
        hipLaunchKernelGGL(ngp_transpose_kernel, dim3(chunks), dim3(256), 0, stream,
                           (const float2*)d_ws, out, B);
    } else {
        const int total = B * NLEV;
        const int blocks = (total + 255) / 256;
        hipLaunchKernelGGL(ngp_embed_fused_kernel, dim3(blocks), dim3(256), 0, stream,
                           x, table, box_min, box_max, out, B);
    }
}

// Round 3
// 310.361 us; speedup vs baseline: 1.4552x; 1.4552x over previous
//
#include <hip/hip_runtime.h>
#include <cstdint>

// Instant-NGP hash-grid embedder, 2-phase with level->XCD affinity.
//
// Journal:
//  R2: level->XCD affinity (blockIdx%8 pins level pairs (i,15-i)); FETCH
//      1.56GB -> 149MB. Phase A ~= 97% of per-XCD L2 request roofline
//      (67.1M random gathers / 8 XCD / 16 ch / 2.4GHz = 218us).
//  R4: no __builtin_nontemporal_* (regressed both phases).
//  R5: phase-B store coalescing: NEUTRAL.  R6: phase-B contiguous chunk-major
//      reads: NEUTRAL.
//  R7: fused tail transpose w/ sc1 stores: FAILED (371us kernel; write-through
//      doubled WRITE, FETCH +45MB, occ 79->69). BUT it measured the hidden
//      per-iteration harness overhead: total 451 - kernel 371 ~= 78us.
//      => phase B's true cost ~= 336-225-78 ~= 33us ~= its 128MB roofline.
//      Phase B is DONE; all remaining budget is phase A.
//  R8 (this): parity-paired x-corner loads. Hash prime for x is 1, so
//      idx(i0+1) = idx(i0)^1 when i0 even -> the two x-corners form one
//      aligned 16B float4. Even-i0 lanes (50%): 4x dwordx4 (4 req) instead
//      of 8x dwordx2 (8 req); odd lanes keep 8x8B under exec mask.
//      Table requests/wave: 512 -> ~384 (-25%). Predict phase A ~170-185us.
//
// Discrete steps (bottom_left trunc) replicated in float64 to match the
// NumPy reference under NEP-50 promotion. Resolutions hardcoded to the
// exact-math floor(16 * 2^(l/3)) values.

constexpr int NLEV = 16;
constexpr uint32_t HM_MASK = (1u << 19) - 1;

__device__ __constant__ double c_res[NLEV] = {
    16.0, 20.0, 25.0, 32.0, 40.0, 50.0, 64.0, 80.0,
    101.0, 128.0, 161.0, 203.0, 256.0, 322.0, 406.0, 512.0
};

__device__ __forceinline__ void ngp_eval_point(
    int b, int lev,
    const float* __restrict__ x,
    const float2* __restrict__ tab2,
    float bm0, float bm1, float bm2,
    float d0, float d1, float d2,
    float& f0, float& f1)
{
    const float fx0 = x[3 * b + 0];
    const float fx1 = x[3 * b + 1];
    const float fx2 = x[3 * b + 2];

    const double res = c_res[lev];
    const double g0 = (double)d0 / res;
    const double g1 = (double)d1 / res;
    const double g2 = (double)d2 / res;
    const double q0 = (double)(fx0 - bm0) / g0;
    const double q1 = (double)(fx1 - bm1) / g1;
    const double q2 = (double)(fx2 - bm2) / g2;
    const int i0 = (int)q0;
    const int i1 = (int)q1;
    const int i2 = (int)q2;
    const float w0 = (float)(q0 - (double)i0);
    const float w1 = (float)(q1 - (double)i1);
    const float w2 = (float)(q2 - (double)i2);

    const uint32_t P1 = 2654435761u, P2 = 805459861u;
    const uint32_t h0a = (uint32_t)i0;
    const uint32_t h1a = (uint32_t)i1 * P1;
    const uint32_t h1b = h1a + P1;
    const uint32_t h2a = (uint32_t)i2 * P2;
    const uint32_t h2b = h2a + P2;
    const uint32_t base = (uint32_t)lev << 19;

    const float u0 = 1.0f - w0, u1 = 1.0f - w1, u2 = 1.0f - w2;
    const float waa = u1 * u2;
    const float wab = u1 * w2;
    const float wba = w1 * u2;
    const float wbb = w1 * w2;

    float acc0 = 0.0f, acc1 = 0.0f;

    if ((h0a & 1u) == 0u) {
        // ---- even i0: x-corner pair {idx, idx^1} is one aligned float4 ----
        // byte addr = ((base+idx)>>1)*16, 16B aligned. Which half is corner
        // x=i0 depends on idx parity (= parity of h1^h2 here).
        const float4* __restrict__ tab4 = (const float4*)tab2;
#define NGP_PAIR(HJK, WYZ)                                                    \
        {                                                                     \
            const uint32_t idx = (h0a ^ (HJK)) & HM_MASK;                     \
            const float4 q = tab4[(base + idx) >> 1];                         \
            const float wlo = (idx & 1u) ? w0 : u0;                           \
            const float whi = (idx & 1u) ? u0 : w0;                           \
            acc0 += (WYZ) * (wlo * q.x + whi * q.z);                          \
            acc1 += (WYZ) * (wlo * q.y + whi * q.w);                          \
        }
        NGP_PAIR(h1a ^ h2a, waa)
        NGP_PAIR(h1a ^ h2b, wab)
        NGP_PAIR(h1b ^ h2a, wba)
        NGP_PAIR(h1b ^ h2b, wbb)
#undef NGP_PAIR
    } else {
        // ---- odd i0: original 8x8B gather path --------------------------
        const uint32_t h0b = h0a + 1u;
        const float2 v000 = tab2[base + ((h0a ^ h1a ^ h2a) & HM_MASK)];
        const float2 v001 = tab2[base + ((h0a ^ h1a ^ h2b) & HM_MASK)];
        const float2 v010 = tab2[base + ((h0a ^ h1b ^ h2a) & HM_MASK)];
        const float2 v011 = tab2[base + ((h0a ^ h1b ^ h2b) & HM_MASK)];
        const float2 v100 = tab2[base + ((h0b ^ h1a ^ h2a) & HM_MASK)];
        const float2 v101 = tab2[base + ((h0b ^ h1a ^ h2b) & HM_MASK)];
        const float2 v110 = tab2[base + ((h0b ^ h1b ^ h2a) & HM_MASK)];
        const float2 v111 = tab2[base + ((h0b ^ h1b ^ h2b) & HM_MASK)];

        acc0 = u0 * (waa * v000.x + wab * v001.x + wba * v010.x + wbb * v011.x)
             + w0 * (waa * v100.x + wab * v101.x + wba * v110.x + wbb * v111.x);
        acc1 = u0 * (waa * v000.y + wab * v001.y + wba * v010.y + wbb * v011.y)
             + w0 * (waa * v100.y + wab * v101.y + wba * v110.y + wbb * v111.y);
    }

    f0 = acc0;
    f1 = acc1;
}

// ---------------- Phase A: per-level gather+interp, level-major ws ----------
// EXACT R2/R0 structure (best measured total: 334-336us).
__global__ __launch_bounds__(256)
void ngp_levels_kernel(const float* __restrict__ x,
                       const float* __restrict__ table,
                       const float* __restrict__ box_min,
                       const float* __restrict__ box_max,
                       float2* __restrict__ ws,
                       int B, int chunks)
{
    // XCD-affinity: residue = blockIdx%8 -> XCD (HW round-robin dispatch).
    // XCD residue i: level i (phase 1, coarse) then 15-i (phase 2, fine).
    const int xcd = blockIdx.x & 7;
    const int s   = blockIdx.x >> 3;
    const int lev   = (s < chunks) ? xcd : (15 - xcd);
    const int chunk = (s < chunks) ? s : (s - chunks);
    const int b = chunk * 256 + threadIdx.x;
    if (b >= B) return;

    const float bm0 = box_min[0], bm1 = box_min[1], bm2 = box_min[2];
    const float d0 = box_max[0] - bm0;
    const float d1 = box_max[1] - bm1;
    const float d2 = box_max[2] - bm2;

    float f0, f1;
    ngp_eval_point(b, lev, x, (const float2*)table,
                   bm0, bm1, bm2, d0, d1, d2, f0, f1);

    ws[(size_t)lev * B + b] = make_float2(f0, f1);  // coalesced 8B
}

// ---------------- Phase B: LDS tile transpose ws[l][b] -> out[b][f*16+l] ----
// Block = 256 points. Requires B % 256 == 0. TRUE COST ~33us ~= roofline
// (established R7); do not touch further.
// LDS layout: float rows indexed r = 2*l + f, row stride 257 floats (pad
// breaks the 32-point bank alias in stage 2). Size = 32*257*4 = 32896 B.
constexpr int LDS_STRIDE = 257;

__global__ __launch_bounds__(256)
void ngp_transpose_kernel(const float2* __restrict__ ws,
                          float* __restrict__ out,
                          int B)
{
    __shared__ float lds[32 * LDS_STRIDE];

    const int t  = threadIdx.x;
    const int P0 = blockIdx.x * 256;

    // Stage 1: coalesced level-row loads (512B per wave-instr) -> LDS.
    // Bank: ((2l*257 + t)) % 32 = (2l + t) % 32 -> 2 lanes/bank (free).
#pragma unroll
    for (int l = 0; l < NLEV; ++l) {
        const float2 v = ws[(size_t)l * B + P0 + t];
        lds[(2 * l)     * LDS_STRIDE + t] = v.x;
        lds[(2 * l + 1) * LDS_STRIDE + t] = v.y;
    }
    __syncthreads();

    // Stage 2: each store instr writes 1KB fully contiguous.
    // Lane t, iter j covers out flat range [P0*32 + j*1024 + 4t, +4):
    //   point p = j*32 + (t>>3), f = (t>>2)&1, l = (t&3)*4 + k.
    const int p_lo = t >> 3;
    const int f    = (t >> 2) & 1;
    const int l0   = (t & 3) * 4;
#pragma unroll
    for (int j = 0; j < 8; ++j) {
        const int p = j * 32 + p_lo;
        float4 v;
        v.x = lds[(2 * (l0 + 0) + f) * LDS_STRIDE + p];
        v.y = lds[(2 * (l0 + 1) + f) * LDS_STRIDE + p];
        v.z = lds[(2 * (l0 + 2) + f) * LDS_STRIDE + p];
        v.w = lds[(2 * (l0 + 3) + f) * LDS_STRIDE + p];
        *(float4*)(out + (size_t)P0 * 32 + j * 1024 + t * 4) = v;
    }
}

// ---------------- Fallback: fused kernel (if ws too small / B%256!=0) -------
__global__ __launch_bounds__(256)
void ngp_embed_fused_kernel(const float* __restrict__ x,
                            const float* __restrict__ table,
                            const float* __restrict__ box_min,
                            const float* __restrict__ box_max,
                            float* __restrict__ out,
                            int B)
{
    const int gid = blockIdx.x * 256 + threadIdx.x;
    const int b = gid >> 4;
    const int l = gid & 15;
    if (b >= B) return;

    const float bm0 = box_min[0], bm1 = box_min[1], bm2 = box_min[2];
    const float d0 = box_max[0] - bm0;
    const float d1 = box_max[1] - bm1;
    const float d2 = box_max[2] - bm2;

    float f0, f1;
    ngp_eval_point(b, l, x, (const float2*)table,
                   bm0, bm1, bm2, d0, d1, d2, f0, f1);

    out[b * 32 + l]      = f0;
    out[b * 32 + 16 + l] = f1;
}

extern "C" void kernel_launch(void* const* d_in, const int* in_sizes, int n_in,
                              void* d_out, int out_size, void* d_ws, size_t ws_size,
                              hipStream_t stream) {
    const float* x       = (const float*)d_in[0];
    const float* table   = (const float*)d_in[1];
    const float* box_min = (const float*)d_in[2];
    const float* box_max = (const float*)d_in[3];
    float* out = (float*)d_out;

    const int B = in_sizes[0] / 3;
    const size_t ws_needed = (size_t)B * NLEV * sizeof(float2);

    if (ws_size >= ws_needed && (B % 256) == 0) {
        const int chunks = B / 256;               // per level, 256 pts/block
        const int gridA = 8 * 2 * chunks;         // 8 residues x 2 levels
        hipLaunchKernelGGL(ngp_levels_kernel, dim3(gridA), dim3(256), 0, stream,
                           x, table, box_min, box_max, (float2*)d_ws, B, chunks);
        const int gridB = B / 256;
        hipLaunchKernelGGL(ngp_transpose_kernel, dim3(gridB), dim3(256), 0, stream,
                           (const float2*)d_ws, out, B);
    } else {
        const int total = B * NLEV;
        const int blocks = (total + 255) / 256;
        hipLaunchKernelGGL(ngp_embed_fused_kernel, dim3(blocks), dim3(256), 0, stream,
                           x, table, box_min, box_max, out, B);
    }
}